// Round 5
// baseline (491.101 us; speedup 1.0000x reference)
//
#include <hip/hip_runtime.h>
#include <math.h>

#define DIM 256
#define NROWS_TILE 128
#define CB 64                       // codes per tile
#define SPLITS 8
#define NCAND SPLITS                // one wave owns each row: 1 slot per split
#define CODES_PER_SPLIT 1024        // K / SPLITS, K = 8192
#define KCH 32                      // k per staged chunk
#define CPT (DIM / KCH)             // 8 chunks per tile
#define NTILES (CODES_PER_SPLIT / CB)   // 16
#define NCHUNKS (NTILES * CPT)      // 128
#define BUF_F16 12288               // f16 per buffer: A 8 frags x2 arr + B 4 frags x2 arr

typedef __attribute__((ext_vector_type(8))) _Float16 f16x8;
typedef __attribute__((ext_vector_type(4))) _Float16 f16x4;
typedef __attribute__((ext_vector_type(4))) float f32x4;

__device__ __forceinline__ void gload16(const void* g, void* l) {
    __builtin_amdgcn_global_load_lds(
        (const __attribute__((address_space(1))) void*)g,
        (__attribute__((address_space(3))) void*)l, 16, 0, 0);
}

__device__ __forceinline__ float waveReduceSum(float v) {
#pragma unroll
    for (int off = 32; off >= 1; off >>= 1) v += __shfl_xor(v, off, 64);
    return v;
}

// ---------- prep: row-l2norm + split-f16 encode (hi + lo*2048) ----------
__global__ __launch_bounds__(256) void k_prep(const float* __restrict__ in,
        _Float16* __restrict__ hi, _Float16* __restrict__ lo,
        float* __restrict__ norms, int nrows)
{
    const int w = threadIdx.x >> 6, lane = threadIdx.x & 63;
    const int r = blockIdx.x * 4 + w;
    if (r >= nrows) return;
    f32x4 v = *(const f32x4*)&in[(size_t)r * DIM + lane * 4];
    float ss = waveReduceSum(v[0]*v[0] + v[1]*v[1] + v[2]*v[2] + v[3]*v[3]);
    const float n = fmaxf(sqrtf(ss), 1e-12f);
    if (norms != nullptr && lane == 0) norms[r] = n;
    f32x4 f;
    f[0] = v[0] / n; f[1] = v[1] / n; f[2] = v[2] / n; f[3] = v[3] / n;
    f16x4 h, l;
#pragma unroll
    for (int c = 0; c < 4; ++c) {
        h[c] = (_Float16)f[c];
        l[c] = (_Float16)((f[c] - (float)h[c]) * 2048.0f);
    }
    *(f16x4*)&hi[(size_t)r * DIM + lane * 4] = h;
    *(f16x4*)&lo[(size_t)r * DIM + lane * 4] = l;
}

// ---------- main: split-f16 MFMA GEMM-BT + fused row argmax ----------
// grid: (N/128 row tiles, SPLITS). Block 256 thr = 4 waves; tile 128x64.
// Wave w owns rows w*32..w*32+31, all 64 cols (no col split -> no cand race).
// 2-buf KCH=32 chunks via global_load_lds; 48 KB LDS -> 3 blocks/CU.
__global__ __launch_bounds__(256, 3) void k_gemm(
    const _Float16* __restrict__ fnh, const _Float16* __restrict__ fnl,
    const _Float16* __restrict__ enh, const _Float16* __restrict__ enl,
    float* __restrict__ cand_val, int* __restrict__ cand_idx)
{
    // buf layout (f16 units): [Ah 8x512 | Al 8x512 | Bh 4x512 | Bl 4x512]
    // frag q = 16 rows of the panel; lane slot: row=lane&15, kgrp=lane>>4.
    __shared__ _Float16 smem[2][BUF_F16];   // 2 x 24 KB

    const int t = threadIdx.x;
    const int w = t >> 6, lane = t & 63;
    const int rbase = blockIdx.x * NROWS_TILE;
    const int cbase = blockIdx.y * CODES_PER_SPLIT;

    // staging roles: w0 fnh(8 frags), w1 fnl(8), w2 enh(4), w3 enl(4)
    const _Float16* const src = (w == 0) ? fnh : (w == 1) ? fnl : (w == 2) ? enh : enl;
    const bool isA = (w < 2);
    const int nq = isA ? 8 : 4;
    const int dstoff = (w == 0) ? 0 : (w == 1) ? 4096 : (w == 2) ? 8192 : 10240;

    float bestv[2][4];
    int   besti[2][4];
#pragma unroll
    for (int i = 0; i < 2; ++i)
#pragma unroll
        for (int rg = 0; rg < 4; ++rg) { bestv[i][rg] = -2.0f; besti[i][rg] = 0; }

    f32x4 acc0[2][4], acc1[2][4];
#pragma unroll
    for (int i = 0; i < 2; ++i)
#pragma unroll
        for (int j = 0; j < 4; ++j) {
            acc0[i][j] = (f32x4){0.f, 0.f, 0.f, 0.f};
            acc1[i][j] = (f32x4){0.f, 0.f, 0.f, 0.f};
        }

    auto STAGE = [&](int c, int buf) {
        const int tile = c >> 3;
        const int kk = (c & (CPT - 1)) * KCH;
        const int rowb = isA ? rbase : (cbase + tile * CB);
        const _Float16* g0 = src + (size_t)(rowb + (lane & 15)) * DIM + kk + (lane >> 4) * 8;
        _Float16* l0 = &smem[buf][dstoff];
        for (int q = 0; q < nq; ++q)
            gload16(g0 + (size_t)q * 16 * DIM, l0 + q * 512);
    };

    STAGE(0, 0);
    asm volatile("s_waitcnt vmcnt(0)" ::: "memory");
    __builtin_amdgcn_s_barrier();

#pragma unroll 1
    for (int c = 0; c < NCHUNKS; ++c) {
        const int buf = c & 1;
        if (c + 1 < NCHUNKS) STAGE(c + 1, buf ^ 1);   // prefetch in flight over compute

        const _Float16* lAh = &smem[buf][0];
        const _Float16* lAl = &smem[buf][4096];
        const _Float16* lBh = &smem[buf][8192];
        const _Float16* lBl = &smem[buf][10240];

        f16x8 Ah[2], Al[2];
#pragma unroll
        for (int i = 0; i < 2; ++i) {
            const int fi = (w * 2 + i) * 512 + lane * 8;
            Ah[i] = *(const f16x8*)(lAh + fi);
            Al[i] = *(const f16x8*)(lAl + fi);
        }
#pragma unroll
        for (int j = 0; j < 4; ++j) {
            const int fj = j * 512 + lane * 8;
            const f16x8 Bh = *(const f16x8*)(lBh + fj);
            const f16x8 Bl = *(const f16x8*)(lBl + fj);
#pragma unroll
            for (int i = 0; i < 2; ++i) {
                acc0[i][j] = __builtin_amdgcn_mfma_f32_16x16x32_f16(Ah[i], Bh, acc0[i][j], 0, 0, 0);
                acc1[i][j] = __builtin_amdgcn_mfma_f32_16x16x32_f16(Ah[i], Bl, acc1[i][j], 0, 0, 0);
                acc1[i][j] = __builtin_amdgcn_mfma_f32_16x16x32_f16(Al[i], Bh, acc1[i][j], 0, 0, 0);
            }
        }

        if ((c & (CPT - 1)) == CPT - 1) {
            // tile finished: fused argmax epilogue (runs while prefetch in flight)
            const int cb = cbase + (c >> 3) * CB;
#pragma unroll
            for (int i = 0; i < 2; ++i) {
#pragma unroll
                for (int rg = 0; rg < 4; ++rg) {
                    float bv = -3e30f; int bix = 0;
#pragma unroll
                    for (int j = 0; j < 4; ++j) {
                        const float vv = acc0[i][j][rg] + acc1[i][j][rg] * (1.0f / 2048.0f);
                        const int ii = cb + j * 16 + (lane & 15);
                        if (vv > bv) { bv = vv; bix = ii; }
                    }
#pragma unroll
                    for (int off = 1; off < 16; off <<= 1) {
                        const float ov = __shfl_xor(bv, off, 16);
                        const int oi = __shfl_xor(bix, off, 16);
                        if (ov > bv || (ov == bv && oi < bix)) { bv = ov; bix = oi; }
                    }
                    if (bv > bestv[i][rg]) { bestv[i][rg] = bv; besti[i][rg] = bix; }
                }
            }
#pragma unroll
            for (int i = 0; i < 2; ++i)
#pragma unroll
                for (int j = 0; j < 4; ++j) {
                    acc0[i][j] = (f32x4){0.f, 0.f, 0.f, 0.f};
                    acc1[i][j] = (f32x4){0.f, 0.f, 0.f, 0.f};
                }
        }

        asm volatile("s_waitcnt vmcnt(0)" ::: "memory");   // next-chunk stage landed
        __builtin_amdgcn_s_barrier();
    }

    // one private slot per (row, split): wave w is sole owner of its 32 rows
    if ((lane & 15) == 0) {
#pragma unroll
        for (int i = 0; i < 2; ++i)
#pragma unroll
            for (int rg = 0; rg < 4; ++rg) {
                const int r = rbase + w * 32 + i * 16 + (lane >> 4) * 4 + rg;
                cand_val[(size_t)r * NCAND + blockIdx.y] = bestv[i][rg];
                cand_idx[(size_t)r * NCAND + blockIdx.y] = besti[i][rg];
            }
    }
}

// ---------- merge splits + gather quantize + scatter embed_sum ----------
__global__ __launch_bounds__(256) void k_merge(
    const float* __restrict__ x, const float* __restrict__ embed,
    const float* __restrict__ cand_val, const int* __restrict__ cand_idx,
    const float* __restrict__ xnorm,
    float* __restrict__ quantize, float* __restrict__ ind_out,
    float* __restrict__ embed_sum, float* __restrict__ bins)
{
    const int w = threadIdx.x >> 6, lane = threadIdx.x & 63;
    const int r = blockIdx.x * 4 + w;
    float v = -3e30f; int ix = 0x7fffffff;
    if (lane < NCAND) {
        v = cand_val[(size_t)r * NCAND + lane];
        ix = cand_idx[(size_t)r * NCAND + lane];
    }
#pragma unroll
    for (int off = 1; off < 8; off <<= 1) {
        const float ov = __shfl_xor(v, off, 8);
        const int oi = __shfl_xor(ix, off, 8);
        if (ov > v || (ov == v && oi < ix)) { v = ov; ix = oi; }
    }
    ix = __shfl(ix, 0, 64);
    if (lane == 0) {
        ind_out[r] = (float)ix;
        atomicAdd(&bins[ix], 1.0f);
    }
    f32x4 e = *(const f32x4*)&embed[(size_t)ix * DIM + lane * 4];
    *(f32x4*)&quantize[(size_t)r * DIM + lane * 4] = e;
    f32x4 xv = *(const f32x4*)&x[(size_t)r * DIM + lane * 4];
    const float n = xnorm[r];
    atomicAdd(&embed_sum[(size_t)ix * DIM + lane * 4 + 0], xv[0] / n);
    atomicAdd(&embed_sum[(size_t)ix * DIM + lane * 4 + 1], xv[1] / n);
    atomicAdd(&embed_sum[(size_t)ix * DIM + lane * 4 + 2], xv[2] / n);
    atomicAdd(&embed_sum[(size_t)ix * DIM + lane * 4 + 3], xv[3] / n);
}

// ---------- EMA update (en recomputed inline) ----------
__global__ __launch_bounds__(256) void k_update(const float* __restrict__ embed,
    const float* __restrict__ embed_sum, const float* __restrict__ bins,
    float* __restrict__ embed_new, int K)
{
    const int w = threadIdx.x >> 6, lane = threadIdx.x & 63;
    const int k = blockIdx.x * 4 + w;
    if (k >= K) return;
    f32x4 e = *(const f32x4*)&embed[(size_t)k * DIM + lane * 4];
    float sse = waveReduceSum(e[0]*e[0] + e[1]*e[1] + e[2]*e[2] + e[3]*e[3]);
    const float ne = fmaxf(sqrtf(sse), 1e-12f);

    const float b = bins[k];
    const float bs = (b == 0.f) ? 1.f : b;
    f32x4 s = *(const f32x4*)&embed_sum[(size_t)k * DIM + lane * 4];
    f32x4 vv;
    vv[0] = s[0] / bs; vv[1] = s[1] / bs; vv[2] = s[2] / bs; vv[3] = s[3] / bs;
    float ssv = waveReduceSum(vv[0]*vv[0] + vv[1]*vv[1] + vv[2]*vv[2] + vv[3]*vv[3]);
    const float nv = fmaxf(sqrtf(ssv), 1e-12f);

    f32x4 o;
#pragma unroll
    for (int c = 0; c < 4; ++c) {
        const float norm_c = (b == 0.f) ? (e[c] / ne) : (vv[c] / nv);
        o[c] = 0.8f * e[c] + 0.2f * norm_c;
    }
    *(f32x4*)&embed_new[(size_t)k * DIM + lane * 4] = o;
}

extern "C" void kernel_launch(void* const* d_in, const int* in_sizes, int n_in,
                              void* d_out, int out_size, void* d_ws, size_t ws_size,
                              hipStream_t stream) {
    const float* x = (const float*)d_in[0];
    const float* embed = (const float*)d_in[1];
    const int N = in_sizes[0] / DIM;   // 16384
    const int K = in_sizes[1] / DIM;   // 8192

    float* quantize  = (float*)d_out;
    float* ind_out   = quantize + (size_t)N * DIM;
    float* embed_new = ind_out + N;

    char* ws = (char*)d_ws;
    _Float16* fnh = (_Float16*)ws;                               // [0, 8M)
    _Float16* fnl = (_Float16*)(ws + (size_t)N * DIM * 2);       // [8M, 16M)
    _Float16* enh = (_Float16*)(ws + (size_t)N * DIM * 4);       // [16M, 20M)
    _Float16* enl = (_Float16*)(ws + (size_t)N * DIM * 4 + (size_t)K * DIM * 2);
    char* p = ws + (size_t)N * DIM * 4 + (size_t)K * DIM * 4;    // 24M
    float* xnorm    = (float*)p;                 p += (size_t)N * 4;
    float* cand_val = (float*)p;                 p += (size_t)N * NCAND * 4;
    int*   cand_idx = (int*)p;
    // embed_sum/bins alias fnh/fnl (dead after k_gemm)
    float* embed_sum = (float*)ws;               // K*DIM floats = 8 MB
    float* bins      = embed_sum + (size_t)K * DIM;

    k_prep<<<(N + 3) / 4, 256, 0, stream>>>(x, fnh, fnl, xnorm, N);
    k_prep<<<(K + 3) / 4, 256, 0, stream>>>(embed, enh, enl, nullptr, K);

    dim3 grid(N / NROWS_TILE, SPLITS);
    k_gemm<<<grid, 256, 0, stream>>>(fnh, fnl, enh, enl, cand_val, cand_idx);

    hipMemsetAsync(embed_sum, 0, ((size_t)K * DIM + K) * sizeof(float), stream);

    k_merge<<<(N + 3) / 4, 256, 0, stream>>>(x, embed, cand_val, cand_idx, xnorm,
                                             quantize, ind_out, embed_sum, bins);
    k_update<<<(K + 3) / 4, 256, 0, stream>>>(embed, embed_sum, bins, embed_new, K);
}

// Round 6
// 463.488 us; speedup vs baseline: 1.0596x; 1.0596x over previous
//
#include <hip/hip_runtime.h>
#include <math.h>

#define DIM 256
#define NROWS_TILE 128
#define CB 64                       // codes per tile
#define SPLITS 8
#define NCAND SPLITS                // one wave owns each row: 1 slot per split
#define CODES_PER_SPLIT 1024        // K / SPLITS, K = 8192
#define KCH 32                      // k per staged chunk
#define CPT (DIM / KCH)             // 8 chunks per tile
#define NTILES (CODES_PER_SPLIT / CB)   // 16
#define NCHUNKS (NTILES * CPT)      // 128
#define BUF_F16 12288               // f16 per buffer: A 8 frags x2 arr + B 4 frags x2 arr
#define NBUF 3

typedef __attribute__((ext_vector_type(8))) _Float16 f16x8;
typedef __attribute__((ext_vector_type(4))) _Float16 f16x4;
typedef __attribute__((ext_vector_type(4))) float f32x4;

__device__ __forceinline__ void gload16(const void* g, void* l) {
    __builtin_amdgcn_global_load_lds(
        (const __attribute__((address_space(1))) void*)g,
        (__attribute__((address_space(3))) void*)l, 16, 0, 0);
}

__device__ __forceinline__ float waveReduceSum(float v) {
#pragma unroll
    for (int off = 32; off >= 1; off >>= 1) v += __shfl_xor(v, off, 64);
    return v;
}

// ---------- prep: row-l2norm + split-f16 encode (hi + lo*2048) ----------
__global__ __launch_bounds__(256) void k_prep(const float* __restrict__ in,
        _Float16* __restrict__ hi, _Float16* __restrict__ lo,
        float* __restrict__ norms, int nrows)
{
    const int w = threadIdx.x >> 6, lane = threadIdx.x & 63;
    const int r = blockIdx.x * 4 + w;
    if (r >= nrows) return;
    f32x4 v = *(const f32x4*)&in[(size_t)r * DIM + lane * 4];
    float ss = waveReduceSum(v[0]*v[0] + v[1]*v[1] + v[2]*v[2] + v[3]*v[3]);
    const float n = fmaxf(sqrtf(ss), 1e-12f);
    if (norms != nullptr && lane == 0) norms[r] = n;
    f32x4 f;
    f[0] = v[0] / n; f[1] = v[1] / n; f[2] = v[2] / n; f[3] = v[3] / n;
    f16x4 h, l;
#pragma unroll
    for (int c = 0; c < 4; ++c) {
        h[c] = (_Float16)f[c];
        l[c] = (_Float16)((f[c] - (float)h[c]) * 2048.0f);
    }
    *(f16x4*)&hi[(size_t)r * DIM + lane * 4] = h;
    *(f16x4*)&lo[(size_t)r * DIM + lane * 4] = l;
}

// ---------- main: split-f16 MFMA GEMM-BT + fused row argmax ----------
// grid: (N/128 row tiles, SPLITS). Block 256 thr = 4 waves; tile 128x64.
// Wave w owns rows w*32..w*32+31, all 64 cols (no col split -> no cand race).
// Ring-3 KCH=32 chunks via global_load_lds, depth-2 prefetch, COUNTED vmcnt:
// iter c waits only its own chunk-c loads (vmcnt(nq), chunk c+1 stays in
// flight) -> barrier -> stage c+2 into buf (c-1)%3 -> compute buf c%3.
__global__ __launch_bounds__(256, 2) void k_gemm(
    const _Float16* __restrict__ fnh, const _Float16* __restrict__ fnl,
    const _Float16* __restrict__ enh, const _Float16* __restrict__ enl,
    float* __restrict__ cand_val, int* __restrict__ cand_idx)
{
    // buf layout (f16 units): [Ah 8x512 | Al 8x512 | Bh 4x512 | Bl 4x512]
    // frag q = 16 rows of the panel; lane slot: row=lane&15, kgrp=lane>>4.
    __shared__ _Float16 smem[NBUF][BUF_F16];   // 3 x 24 KB

    const int t = threadIdx.x;
    const int w = t >> 6, lane = t & 63;
    const int rbase = blockIdx.x * NROWS_TILE;
    const int cbase = blockIdx.y * CODES_PER_SPLIT;

    // staging roles: w0 fnh(8 frags), w1 fnl(8), w2 enh(4), w3 enl(4)
    const _Float16* const src = (w == 0) ? fnh : (w == 1) ? fnl : (w == 2) ? enh : enl;
    const bool isA = (w < 2);
    const int dstoff = (w == 0) ? 0 : (w == 1) ? 4096 : (w == 2) ? 8192 : 10240;

    float bestv[2][4];
    int   besti[2][4];
#pragma unroll
    for (int i = 0; i < 2; ++i)
#pragma unroll
        for (int rg = 0; rg < 4; ++rg) { bestv[i][rg] = -2.0f; besti[i][rg] = 0; }

    f32x4 acc0[2][4], acc1[2][4];
#pragma unroll
    for (int i = 0; i < 2; ++i)
#pragma unroll
        for (int j = 0; j < 4; ++j) {
            acc0[i][j] = (f32x4){0.f, 0.f, 0.f, 0.f};
            acc1[i][j] = (f32x4){0.f, 0.f, 0.f, 0.f};
        }

    auto STAGE = [&](int c, int buf) {
        const int tile = c >> 3;
        const int kk = (c & (CPT - 1)) * KCH;
        const int rowb = isA ? rbase : (cbase + tile * CB);
        const _Float16* g0 = src + (size_t)(rowb + (lane & 15)) * DIM + kk + (lane >> 4) * 8;
        _Float16* l0 = &smem[buf][dstoff];
        if (isA) {
#pragma unroll
            for (int q = 0; q < 8; ++q)
                gload16(g0 + (size_t)q * 16 * DIM, l0 + q * 512);
        } else {
#pragma unroll
            for (int q = 0; q < 4; ++q)
                gload16(g0 + (size_t)q * 16 * DIM, l0 + q * 512);
        }
    };

    // prologue: two chunks in flight
    STAGE(0, 0);
    STAGE(1, 1);

    int cur = 0;   // buffer holding chunk c
#pragma unroll 1
    for (int c = 0; c < NCHUNKS; ++c) {
        // wait own chunk-c loads only (chunk c+1 stays in flight), then publish
        if (c == NCHUNKS - 1)
            asm volatile("s_waitcnt vmcnt(0)" ::: "memory");
        else if (isA)
            asm volatile("s_waitcnt vmcnt(8)" ::: "memory");
        else
            asm volatile("s_waitcnt vmcnt(4)" ::: "memory");
        __builtin_amdgcn_s_barrier();

        if (c + 2 < NCHUNKS) {
            int sb = cur - 1; if (sb < 0) sb += NBUF;   // (c+2)%3 == (c-1)%3
            STAGE(c + 2, sb);
        }

        const _Float16* lAh = &smem[cur][0];
        const _Float16* lAl = &smem[cur][4096];
        const _Float16* lBh = &smem[cur][8192];
        const _Float16* lBl = &smem[cur][10240];

        f16x8 Ah[2], Al[2];
#pragma unroll
        for (int i = 0; i < 2; ++i) {
            const int fi = (w * 2 + i) * 512 + lane * 8;
            Ah[i] = *(const f16x8*)(lAh + fi);
            Al[i] = *(const f16x8*)(lAl + fi);
        }
#pragma unroll
        for (int j = 0; j < 4; ++j) {
            const int fj = j * 512 + lane * 8;
            const f16x8 Bh = *(const f16x8*)(lBh + fj);
            const f16x8 Bl = *(const f16x8*)(lBl + fj);
#pragma unroll
            for (int i = 0; i < 2; ++i) {
                acc0[i][j] = __builtin_amdgcn_mfma_f32_16x16x32_f16(Ah[i], Bh, acc0[i][j], 0, 0, 0);
                acc1[i][j] = __builtin_amdgcn_mfma_f32_16x16x32_f16(Ah[i], Bl, acc1[i][j], 0, 0, 0);
                acc1[i][j] = __builtin_amdgcn_mfma_f32_16x16x32_f16(Al[i], Bh, acc1[i][j], 0, 0, 0);
            }
        }

        if ((c & (CPT - 1)) == CPT - 1) {
            // tile finished: fused argmax epilogue (runs while prefetch in flight)
            const int cb = cbase + (c >> 3) * CB;
#pragma unroll
            for (int i = 0; i < 2; ++i) {
#pragma unroll
                for (int rg = 0; rg < 4; ++rg) {
                    float bv = -3e30f; int bix = 0;
#pragma unroll
                    for (int j = 0; j < 4; ++j) {
                        const float vv = acc0[i][j][rg] + acc1[i][j][rg] * (1.0f / 2048.0f);
                        const int ii = cb + j * 16 + (lane & 15);
                        if (vv > bv) { bv = vv; bix = ii; }
                    }
#pragma unroll
                    for (int off = 1; off < 16; off <<= 1) {
                        const float ov = __shfl_xor(bv, off, 16);
                        const int oi = __shfl_xor(bix, off, 16);
                        if (ov > bv || (ov == bv && oi < bix)) { bv = ov; bix = oi; }
                    }
                    if (bv > bestv[i][rg]) { bestv[i][rg] = bv; besti[i][rg] = bix; }
                }
            }
#pragma unroll
            for (int i = 0; i < 2; ++i)
#pragma unroll
                for (int j = 0; j < 4; ++j) {
                    acc0[i][j] = (f32x4){0.f, 0.f, 0.f, 0.f};
                    acc1[i][j] = (f32x4){0.f, 0.f, 0.f, 0.f};
                }
        }

        cur = (cur == NBUF - 1) ? 0 : cur + 1;
    }

    // one private slot per (row, split): wave w is sole owner of its 32 rows
    if ((lane & 15) == 0) {
#pragma unroll
        for (int i = 0; i < 2; ++i)
#pragma unroll
            for (int rg = 0; rg < 4; ++rg) {
                const int r = rbase + w * 32 + i * 16 + (lane >> 4) * 4 + rg;
                cand_val[(size_t)r * NCAND + blockIdx.y] = bestv[i][rg];
                cand_idx[(size_t)r * NCAND + blockIdx.y] = besti[i][rg];
            }
    }
}

// ---------- merge splits + gather quantize + scatter embed_sum ----------
__global__ __launch_bounds__(256) void k_merge(
    const float* __restrict__ x, const float* __restrict__ embed,
    const float* __restrict__ cand_val, const int* __restrict__ cand_idx,
    const float* __restrict__ xnorm,
    float* __restrict__ quantize, float* __restrict__ ind_out,
    float* __restrict__ embed_sum, float* __restrict__ bins)
{
    const int w = threadIdx.x >> 6, lane = threadIdx.x & 63;
    const int r = blockIdx.x * 4 + w;
    float v = -3e30f; int ix = 0x7fffffff;
    if (lane < NCAND) {
        v = cand_val[(size_t)r * NCAND + lane];
        ix = cand_idx[(size_t)r * NCAND + lane];
    }
#pragma unroll
    for (int off = 1; off < 8; off <<= 1) {
        const float ov = __shfl_xor(v, off, 8);
        const int oi = __shfl_xor(ix, off, 8);
        if (ov > v || (ov == v && oi < ix)) { v = ov; ix = oi; }
    }
    ix = __shfl(ix, 0, 64);
    if (lane == 0) {
        ind_out[r] = (float)ix;
        atomicAdd(&bins[ix], 1.0f);
    }
    f32x4 e = *(const f32x4*)&embed[(size_t)ix * DIM + lane * 4];
    *(f32x4*)&quantize[(size_t)r * DIM + lane * 4] = e;
    f32x4 xv = *(const f32x4*)&x[(size_t)r * DIM + lane * 4];
    const float n = xnorm[r];
    atomicAdd(&embed_sum[(size_t)ix * DIM + lane * 4 + 0], xv[0] / n);
    atomicAdd(&embed_sum[(size_t)ix * DIM + lane * 4 + 1], xv[1] / n);
    atomicAdd(&embed_sum[(size_t)ix * DIM + lane * 4 + 2], xv[2] / n);
    atomicAdd(&embed_sum[(size_t)ix * DIM + lane * 4 + 3], xv[3] / n);
}

// ---------- EMA update (en recomputed inline) ----------
__global__ __launch_bounds__(256) void k_update(const float* __restrict__ embed,
    const float* __restrict__ embed_sum, const float* __restrict__ bins,
    float* __restrict__ embed_new, int K)
{
    const int w = threadIdx.x >> 6, lane = threadIdx.x & 63;
    const int k = blockIdx.x * 4 + w;
    if (k >= K) return;
    f32x4 e = *(const f32x4*)&embed[(size_t)k * DIM + lane * 4];
    float sse = waveReduceSum(e[0]*e[0] + e[1]*e[1] + e[2]*e[2] + e[3]*e[3]);
    const float ne = fmaxf(sqrtf(sse), 1e-12f);

    const float b = bins[k];
    const float bs = (b == 0.f) ? 1.f : b;
    f32x4 s = *(const f32x4*)&embed_sum[(size_t)k * DIM + lane * 4];
    f32x4 vv;
    vv[0] = s[0] / bs; vv[1] = s[1] / bs; vv[2] = s[2] / bs; vv[3] = s[3] / bs;
    float ssv = waveReduceSum(vv[0]*vv[0] + vv[1]*vv[1] + vv[2]*vv[2] + vv[3]*vv[3]);
    const float nv = fmaxf(sqrtf(ssv), 1e-12f);

    f32x4 o;
#pragma unroll
    for (int c = 0; c < 4; ++c) {
        const float norm_c = (b == 0.f) ? (e[c] / ne) : (vv[c] / nv);
        o[c] = 0.8f * e[c] + 0.2f * norm_c;
    }
    *(f32x4*)&embed_new[(size_t)k * DIM + lane * 4] = o;
}

extern "C" void kernel_launch(void* const* d_in, const int* in_sizes, int n_in,
                              void* d_out, int out_size, void* d_ws, size_t ws_size,
                              hipStream_t stream) {
    const float* x = (const float*)d_in[0];
    const float* embed = (const float*)d_in[1];
    const int N = in_sizes[0] / DIM;   // 16384
    const int K = in_sizes[1] / DIM;   // 8192

    float* quantize  = (float*)d_out;
    float* ind_out   = quantize + (size_t)N * DIM;
    float* embed_new = ind_out + N;

    char* ws = (char*)d_ws;
    _Float16* fnh = (_Float16*)ws;                               // [0, 8M)
    _Float16* fnl = (_Float16*)(ws + (size_t)N * DIM * 2);       // [8M, 16M)
    _Float16* enh = (_Float16*)(ws + (size_t)N * DIM * 4);       // [16M, 20M)
    _Float16* enl = (_Float16*)(ws + (size_t)N * DIM * 4 + (size_t)K * DIM * 2);
    char* p = ws + (size_t)N * DIM * 4 + (size_t)K * DIM * 4;    // 24M
    float* xnorm    = (float*)p;                 p += (size_t)N * 4;
    float* cand_val = (float*)p;                 p += (size_t)N * NCAND * 4;
    int*   cand_idx = (int*)p;
    // embed_sum/bins alias fnh/fnl (dead after k_gemm)
    float* embed_sum = (float*)ws;               // K*DIM floats = 8 MB
    float* bins      = embed_sum + (size_t)K * DIM;

    k_prep<<<(N + 3) / 4, 256, 0, stream>>>(x, fnh, fnl, xnorm, N);
    k_prep<<<(K + 3) / 4, 256, 0, stream>>>(embed, enh, enl, nullptr, K);

    dim3 grid(N / NROWS_TILE, SPLITS);
    k_gemm<<<grid, 256, 0, stream>>>(fnh, fnl, enh, enl, cand_val, cand_idx);

    hipMemsetAsync(embed_sum, 0, ((size_t)K * DIM + K) * sizeof(float), stream);

    k_merge<<<(N + 3) / 4, 256, 0, stream>>>(x, embed, cand_val, cand_idx, xnorm,
                                             quantize, ind_out, embed_sum, bins);
    k_update<<<(K + 3) / 4, 256, 0, stream>>>(embed, embed_sum, bins, embed_new, K);
}

// Round 7
// 263.099 us; speedup vs baseline: 1.8666x; 1.7617x over previous
//
#include <hip/hip_runtime.h>
#include <math.h>

#define DIM 256
#define NROWS_TILE 128
#define SPLITS 8
#define NCAND SPLITS                // one wave owns each row: 1 slot per split
#define CODES_PER_SPLIT 1024        // K / SPLITS, K = 8192
#define CCH 16                      // codes per staged chunk (full K=256 per chunk)
#define NCH (CODES_PER_SPLIT / CCH) // 64 phases
#define NBUF 3
#define BUF_F16 8192                // 16 KB: [enh 8 frags x 512 | enl 8 frags x 512]

typedef __attribute__((ext_vector_type(8))) _Float16 f16x8;
typedef __attribute__((ext_vector_type(4))) _Float16 f16x4;
typedef __attribute__((ext_vector_type(4))) float f32x4;

__device__ __forceinline__ void gload16(const void* g, void* l) {
    __builtin_amdgcn_global_load_lds(
        (const __attribute__((address_space(1))) void*)g,
        (__attribute__((address_space(3))) void*)l, 16, 0, 0);
}

__device__ __forceinline__ float waveReduceSum(float v) {
#pragma unroll
    for (int off = 32; off >= 1; off >>= 1) v += __shfl_xor(v, off, 64);
    return v;
}

// ---------- prep: row-l2norm + split-f16 encode (hi + lo*2048) ----------
__global__ __launch_bounds__(256) void k_prep(const float* __restrict__ in,
        _Float16* __restrict__ hi, _Float16* __restrict__ lo,
        float* __restrict__ norms, int nrows)
{
    const int w = threadIdx.x >> 6, lane = threadIdx.x & 63;
    const int r = blockIdx.x * 4 + w;
    if (r >= nrows) return;
    f32x4 v = *(const f32x4*)&in[(size_t)r * DIM + lane * 4];
    float ss = waveReduceSum(v[0]*v[0] + v[1]*v[1] + v[2]*v[2] + v[3]*v[3]);
    const float n = fmaxf(sqrtf(ss), 1e-12f);
    if (norms != nullptr && lane == 0) norms[r] = n;
    f32x4 f;
    f[0] = v[0] / n; f[1] = v[1] / n; f[2] = v[2] / n; f[3] = v[3] / n;
    f16x4 h, l;
#pragma unroll
    for (int c = 0; c < 4; ++c) {
        h[c] = (_Float16)f[c];
        l[c] = (_Float16)((f[c] - (float)h[c]) * 2048.0f);
    }
    *(f16x4*)&hi[(size_t)r * DIM + lane * 4] = h;
    *(f16x4*)&lo[(size_t)r * DIM + lane * 4] = l;
}

// ---------- main: split-f16 MFMA GEMM-BT, A resident in registers ----------
// grid: (N/128 row tiles, SPLITS). Block 256 thr = 4 waves; wave owns 32 rows
// x full K=256 in VGPRs (Ah/Al 32 x f16x8 = 128 regs). Loop stages only B:
// chunk = 16 codes x 256 k x {hi,lo} = 16 KB, ring-3, counted vmcnt (depth-2).
// Per phase per wave: 4 gload_lds + 16 ds_read_b128 + 48 MFMA; argmax is
// lane-local (code = cb + (lane&15)), butterfly once at the end.
__global__ __launch_bounds__(256, 2) void k_gemm(
    const _Float16* __restrict__ fnh, const _Float16* __restrict__ fnl,
    const _Float16* __restrict__ enh, const _Float16* __restrict__ enl,
    float* __restrict__ cand_val, int* __restrict__ cand_idx)
{
    // buf: [enh: kc 0..7 frags of 512 f16 | enl: +4096]. frag slot: lane*8 f16
    // = (code=lane&15, kgrp=lane>>4), i.e. en[(cb+(lane&15))*256 + kc*32 + kgrp*8].
    __shared__ _Float16 smem[NBUF][BUF_F16];   // 3 x 16 KB

    const int t = threadIdx.x;
    const int w = t >> 6, lane = t & 63;
    const int rbase = blockIdx.x * NROWS_TILE;
    const int cbase = blockIdx.y * CODES_PER_SPLIT;
    const int koff = (lane >> 4) * 8;

    // ---- A panel into registers: wave w rows rbase+w*32 .. +31, full K ----
    f16x8 Ah[2][8], Al[2][8];
    {
        const size_t arow = (size_t)(rbase + w * 32 + (lane & 15)) * DIM;
#pragma unroll
        for (int i = 0; i < 2; ++i)
#pragma unroll
            for (int kc = 0; kc < 8; ++kc) {
                Ah[i][kc] = *(const f16x8*)&fnh[arow + (size_t)i * 16 * DIM + kc * 32 + koff];
                Al[i][kc] = *(const f16x8*)&fnl[arow + (size_t)i * 16 * DIM + kc * 32 + koff];
            }
    }
    asm volatile("s_waitcnt vmcnt(0)" ::: "memory");   // A complete before staging counts

    // staging roles: wave w stages frags f = w*4 .. w*4+3 (f = mat*8 + kc)
    const _Float16* const bsrc = (w < 2) ? enh : enl;
    const int kcb = (w & 1) * 4;
    const int ldsoff = (w >> 1) * 4096 + kcb * 512;

    auto STAGE = [&](int c, int buf) {
        const int cb = cbase + c * CCH;
        const _Float16* g0 = bsrc + (size_t)(cb + (lane & 15)) * DIM + kcb * 32 + koff;
        _Float16* l0 = &smem[buf][ldsoff];
#pragma unroll
        for (int q = 0; q < 4; ++q)
            gload16(g0 + q * 32, l0 + q * 512);
    };

    float bestv[2][4];
    int   bestc[2][4];
#pragma unroll
    for (int i = 0; i < 2; ++i)
#pragma unroll
        for (int rg = 0; rg < 4; ++rg) { bestv[i][rg] = -2.0f; bestc[i][rg] = 0; }

    // prologue: two chunks in flight
    STAGE(0, 0);
    STAGE(1, 1);

    int cur = 0;
#pragma unroll 1
    for (int c = 0; c < NCH; ++c) {
        if (c == NCH - 1)
            asm volatile("s_waitcnt vmcnt(0)" ::: "memory");
        else
            asm volatile("s_waitcnt vmcnt(4)" ::: "memory");   // chunk c landed; c+1 in flight
        __builtin_amdgcn_s_barrier();

        if (c + 2 < NCH) {
            int sb = cur - 1; if (sb < 0) sb += NBUF;   // (c+2)%3
            STAGE(c + 2, sb);
        }

        f32x4 acc0[2], acc1a[2], acc1b[2];
#pragma unroll
        for (int i = 0; i < 2; ++i) {
            acc0[i]  = (f32x4){0.f, 0.f, 0.f, 0.f};
            acc1a[i] = (f32x4){0.f, 0.f, 0.f, 0.f};
            acc1b[i] = (f32x4){0.f, 0.f, 0.f, 0.f};
        }

#pragma unroll
        for (int kc = 0; kc < 8; ++kc) {
            const f16x8 Bh = *(const f16x8*)&smem[cur][kc * 512 + lane * 8];
            const f16x8 Bl = *(const f16x8*)&smem[cur][4096 + kc * 512 + lane * 8];
#pragma unroll
            for (int i = 0; i < 2; ++i) {
                acc0[i]  = __builtin_amdgcn_mfma_f32_16x16x32_f16(Ah[i][kc], Bh, acc0[i],  0, 0, 0);
                acc1a[i] = __builtin_amdgcn_mfma_f32_16x16x32_f16(Ah[i][kc], Bl, acc1a[i], 0, 0, 0);
                acc1b[i] = __builtin_amdgcn_mfma_f32_16x16x32_f16(Al[i][kc], Bh, acc1b[i], 0, 0, 0);
            }
        }

        // lane-local argmax update (code = cb + (lane&15)); strict > keeps
        // earliest phase on ties = jnp first-occurrence.
        const int cb = cbase + c * CCH;
#pragma unroll
        for (int i = 0; i < 2; ++i)
#pragma unroll
            for (int rg = 0; rg < 4; ++rg) {
                const float vv = acc0[i][rg] + (acc1a[i][rg] + acc1b[i][rg]) * (1.0f / 2048.0f);
                if (vv > bestv[i][rg]) { bestv[i][rg] = vv; bestc[i][rg] = cb; }
            }

        cur = (cur == NBUF - 1) ? 0 : cur + 1;
    }

    // final cross-lane argmax (width 16), min-index tie-break
#pragma unroll
    for (int i = 0; i < 2; ++i)
#pragma unroll
        for (int rg = 0; rg < 4; ++rg) {
            float bv = bestv[i][rg];
            int bix = bestc[i][rg] + (lane & 15);
#pragma unroll
            for (int off = 1; off < 16; off <<= 1) {
                const float ov = __shfl_xor(bv, off, 16);
                const int oi = __shfl_xor(bix, off, 16);
                if (ov > bv || (ov == bv && oi < bix)) { bv = ov; bix = oi; }
            }
            if ((lane & 15) == 0) {
                const int r = rbase + w * 32 + i * 16 + (lane >> 4) * 4 + rg;
                cand_val[(size_t)r * NCAND + blockIdx.y] = bv;
                cand_idx[(size_t)r * NCAND + blockIdx.y] = bix;
            }
        }
}

// ---------- merge splits + gather quantize + scatter embed_sum ----------
__global__ __launch_bounds__(256) void k_merge(
    const float* __restrict__ x, const float* __restrict__ embed,
    const float* __restrict__ cand_val, const int* __restrict__ cand_idx,
    const float* __restrict__ xnorm,
    float* __restrict__ quantize, float* __restrict__ ind_out,
    float* __restrict__ embed_sum, float* __restrict__ bins)
{
    const int w = threadIdx.x >> 6, lane = threadIdx.x & 63;
    const int r = blockIdx.x * 4 + w;
    float v = -3e30f; int ix = 0x7fffffff;
    if (lane < NCAND) {
        v = cand_val[(size_t)r * NCAND + lane];
        ix = cand_idx[(size_t)r * NCAND + lane];
    }
#pragma unroll
    for (int off = 1; off < 8; off <<= 1) {
        const float ov = __shfl_xor(v, off, 8);
        const int oi = __shfl_xor(ix, off, 8);
        if (ov > v || (ov == v && oi < ix)) { v = ov; ix = oi; }
    }
    ix = __shfl(ix, 0, 64);
    if (lane == 0) {
        ind_out[r] = (float)ix;
        atomicAdd(&bins[ix], 1.0f);
    }
    f32x4 e = *(const f32x4*)&embed[(size_t)ix * DIM + lane * 4];
    *(f32x4*)&quantize[(size_t)r * DIM + lane * 4] = e;
    f32x4 xv = *(const f32x4*)&x[(size_t)r * DIM + lane * 4];
    const float n = xnorm[r];
    atomicAdd(&embed_sum[(size_t)ix * DIM + lane * 4 + 0], xv[0] / n);
    atomicAdd(&embed_sum[(size_t)ix * DIM + lane * 4 + 1], xv[1] / n);
    atomicAdd(&embed_sum[(size_t)ix * DIM + lane * 4 + 2], xv[2] / n);
    atomicAdd(&embed_sum[(size_t)ix * DIM + lane * 4 + 3], xv[3] / n);
}

// ---------- EMA update (en recomputed inline) ----------
__global__ __launch_bounds__(256) void k_update(const float* __restrict__ embed,
    const float* __restrict__ embed_sum, const float* __restrict__ bins,
    float* __restrict__ embed_new, int K)
{
    const int w = threadIdx.x >> 6, lane = threadIdx.x & 63;
    const int k = blockIdx.x * 4 + w;
    if (k >= K) return;
    f32x4 e = *(const f32x4*)&embed[(size_t)k * DIM + lane * 4];
    float sse = waveReduceSum(e[0]*e[0] + e[1]*e[1] + e[2]*e[2] + e[3]*e[3]);
    const float ne = fmaxf(sqrtf(sse), 1e-12f);

    const float b = bins[k];
    const float bs = (b == 0.f) ? 1.f : b;
    f32x4 s = *(const f32x4*)&embed_sum[(size_t)k * DIM + lane * 4];
    f32x4 vv;
    vv[0] = s[0] / bs; vv[1] = s[1] / bs; vv[2] = s[2] / bs; vv[3] = s[3] / bs;
    float ssv = waveReduceSum(vv[0]*vv[0] + vv[1]*vv[1] + vv[2]*vv[2] + vv[3]*vv[3]);
    const float nv = fmaxf(sqrtf(ssv), 1e-12f);

    f32x4 o;
#pragma unroll
    for (int c = 0; c < 4; ++c) {
        const float norm_c = (b == 0.f) ? (e[c] / ne) : (vv[c] / nv);
        o[c] = 0.8f * e[c] + 0.2f * norm_c;
    }
    *(f32x4*)&embed_new[(size_t)k * DIM + lane * 4] = o;
}

extern "C" void kernel_launch(void* const* d_in, const int* in_sizes, int n_in,
                              void* d_out, int out_size, void* d_ws, size_t ws_size,
                              hipStream_t stream) {
    const float* x = (const float*)d_in[0];
    const float* embed = (const float*)d_in[1];
    const int N = in_sizes[0] / DIM;   // 16384
    const int K = in_sizes[1] / DIM;   // 8192

    float* quantize  = (float*)d_out;
    float* ind_out   = quantize + (size_t)N * DIM;
    float* embed_new = ind_out + N;

    char* ws = (char*)d_ws;
    _Float16* fnh = (_Float16*)ws;                               // [0, 8M)
    _Float16* fnl = (_Float16*)(ws + (size_t)N * DIM * 2);       // [8M, 16M)
    _Float16* enh = (_Float16*)(ws + (size_t)N * DIM * 4);       // [16M, 20M)
    _Float16* enl = (_Float16*)(ws + (size_t)N * DIM * 4 + (size_t)K * DIM * 2);
    char* p = ws + (size_t)N * DIM * 4 + (size_t)K * DIM * 4;    // 24M
    float* xnorm    = (float*)p;                 p += (size_t)N * 4;
    float* cand_val = (float*)p;                 p += (size_t)N * NCAND * 4;
    int*   cand_idx = (int*)p;
    // embed_sum/bins alias fnh/fnl (dead after k_gemm)
    float* embed_sum = (float*)ws;               // K*DIM floats = 8 MB
    float* bins      = embed_sum + (size_t)K * DIM;

    k_prep<<<(N + 3) / 4, 256, 0, stream>>>(x, fnh, fnl, xnorm, N);
    k_prep<<<(K + 3) / 4, 256, 0, stream>>>(embed, enh, enl, nullptr, K);

    dim3 grid(N / NROWS_TILE, SPLITS);
    k_gemm<<<grid, 256, 0, stream>>>(fnh, fnl, enh, enl, cand_val, cand_idx);

    hipMemsetAsync(embed_sum, 0, ((size_t)K * DIM + K) * sizeof(float), stream);

    k_merge<<<(N + 3) / 4, 256, 0, stream>>>(x, embed, cand_val, cand_idx, xnorm,
                                             quantize, ind_out, embed_sum, bins);
    k_update<<<(K + 3) / 4, 256, 0, stream>>>(embed, embed_sum, bins, embed_new, K);
}